// Round 1
// baseline (751.973 us; speedup 1.0000x reference)
//
#include <hip/hip_runtime.h>
#include <hip/hip_bf16.h>

#define B_    32
#define S_    512
#define C_    16
#define DIN_  256
#define DOUT_ 64

typedef __bf16 bf16x8 __attribute__((ext_vector_type(8)));
typedef float  f32x16 __attribute__((ext_vector_type(16)));

// Split fp32 -> bf16 hi + bf16 lo (lo = RNE(f - float(hi))); hi*hi + hi*lo + lo*hi
// reproduces the fp32 product to ~2^-17 relative.
__device__ inline void split2(float f, __bf16& hi, __bf16& lo) {
    hi = (__bf16)f;
    lo = (__bf16)(f - (float)hi);
}

// u_hat[b,c,s,o] = sum_i x[b,s,i] * W[c,s,i,o]  via MFMA 32x32x16 (split-bf16, 3 mfma/k-block).
// One wave per (c,s): A = x[0:32, s, :] (m=b), B = W[c,s,:,:] (n=o, two 32-col halves).
// All loads lane-varying and fully coalesced (A: 2x float4/lane; B: per-j 2x128B segments).
// W is streamed once with NO reuse -> nontemporal (evict-first) so the 537 MB stream does
// not evict the 64 MB u_hat from L2/L3 before the routing passes read it.
// NO atomics (R4: the 16.7M device-scope atomicAdds were the prime stall suspect);
// iter-0 s-sum moved to sum0_squash.
__global__ __launch_bounds__(256) void gemm_uhat(
    const float* __restrict__ x, const float* __restrict__ W,
    float* __restrict__ u_hat) {
    const int lane = threadIdx.x & 63;
    const int wid  = threadIdx.x >> 6;
    const int s    = blockIdx.x >> 2;                 // 4 blocks per s
    const int c    = ((blockIdx.x & 3) << 2) + wid;   // 4 waves = 4 capsules, same s -> x L1 reuse
    const int m    = lane & 31;                       // A row (b) / B col (o)
    const int kh   = lane >> 5;                       // k-half: k = kh*8 + j

    const float* xp = x + ((size_t)m * S_ + s) * DIN_ + kh * 8;
    const float* wp = W + (((size_t)c * S_ + s) * DIN_ + kh * 8) * DOUT_ + m;

    f32x16 acc0, acc1;
#pragma unroll
    for (int r = 0; r < 16; ++r) { acc0[r] = 0.f; acc1[r] = 0.f; }

#pragma unroll 1
    for (int kb = 0; kb < DIN_ / 16; ++kb) {
        const float4 a0 = *(const float4*)(xp);
        const float4 a1 = *(const float4*)(xp + 4);
        xp += 16;
        float wa[8], wb[8];
#pragma unroll
        for (int j = 0; j < 8; ++j) {
            wa[j] = __builtin_nontemporal_load(wp + j * DOUT_);        // W[.., kh*8+j, m]
            wb[j] = __builtin_nontemporal_load(wp + j * DOUT_ + 32);   // W[.., kh*8+j, m+32]
        }
        wp += 16 * DOUT_;

        const float af[8] = {a0.x, a0.y, a0.z, a0.w, a1.x, a1.y, a1.z, a1.w};
        bf16x8 ahi, alo, b0hi, b0lo, b1hi, b1lo;
#pragma unroll
        for (int j = 0; j < 8; ++j) {
            __bf16 h, l;
            split2(af[j], h, l); ahi[j] = h; alo[j] = l;
            split2(wa[j], h, l); b0hi[j] = h; b0lo[j] = l;
            split2(wb[j], h, l); b1hi[j] = h; b1lo[j] = l;
        }
        acc0 = __builtin_amdgcn_mfma_f32_32x32x16_bf16(ahi, b0hi, acc0, 0, 0, 0);
        acc0 = __builtin_amdgcn_mfma_f32_32x32x16_bf16(ahi, b0lo, acc0, 0, 0, 0);
        acc0 = __builtin_amdgcn_mfma_f32_32x32x16_bf16(alo, b0hi, acc0, 0, 0, 0);
        acc1 = __builtin_amdgcn_mfma_f32_32x32x16_bf16(ahi, b1hi, acc1, 0, 0, 0);
        acc1 = __builtin_amdgcn_mfma_f32_32x32x16_bf16(ahi, b1lo, acc1, 0, 0, 0);
        acc1 = __builtin_amdgcn_mfma_f32_32x32x16_bf16(alo, b1hi, acc1, 0, 0, 0);
    }

    // C/D layout (HW-verified m74/m101): col(o) = lane&31, row(b) = (r&3) + 8*(r>>2) + 4*kh
#pragma unroll
    for (int r = 0; r < 16; ++r) {
        const int b = (r & 3) + 8 * (r >> 2) + 4 * kh;
        const size_t base = (((size_t)b * C_ + c) * S_ + s) * DOUT_;
        u_hat[base + m]      = acc0[r];
        u_hat[base + m + 32] = acc1[r];
    }
}

// v0 = squash((1/16) * sum_s u_hat[b,c,s,:])  -- softmax of zero logits is uniform 1/C.
// One block per (b,c): 16 waves stream the 128 KB row (coalesced 256B/instr, L3-resident),
// LDS cross-wave reduce, wave 0 does the shfl-norm + squash. Replaces the gemm atomics.
__global__ __launch_bounds__(1024) void sum0_squash(
    const float* __restrict__ u_hat, float* __restrict__ v_out) {
    const int lane = threadIdx.x & 63;
    const int w    = threadIdx.x >> 6;       // 0..15
    const int idx  = blockIdx.x;             // b*C + c
    const float* up = u_hat + (size_t)idx * S_ * DOUT_ + lane;
    float acc = 0.f;
#pragma unroll 4
    for (int s = w; s < S_; s += 16)
        acc += up[(size_t)s * DOUT_];
    __shared__ float red[16][DOUT_];
    red[w][lane] = acc;
    __syncthreads();
    if (w == 0) {
        float t = 0.f;
#pragma unroll
        for (int g = 0; g < 16; ++g) t += red[g][lane];
        t *= 0.0625f;
        float ss = t * t;
#pragma unroll
        for (int off = 32; off; off >>= 1) ss += __shfl_xor(ss, off);
        const float n = sqrtf(ss);
        v_out[(size_t)idx * DOUT_ + lane] = t * (n / (1.f + ss));
    }
}

// v = squash(sum_p parts[b,p,c,:]) -- final reduce of the 32 per-chunk partials + squash.
__global__ __launch_bounds__(64) void part_squash(
    const float* __restrict__ parts, float* __restrict__ dst) {
    const int lane = threadIdx.x;
    const int b = blockIdx.x >> 4;           // blockIdx = b*C + c
    const int c = blockIdx.x & 15;
    float t = 0.f;
#pragma unroll
    for (int p = 0; p < 32; ++p)
        t += parts[(((size_t)b * 32 + p) * C_ + c) * DOUT_ + lane];
    float ss = t * t;
#pragma unroll
    for (int off = 32; off; off >>= 1) ss += __shfl_xor(ss, off);
    const float n = sqrtf(ss);
    dst[(size_t)blockIdx.x * DOUT_ + lane] = t * (n / (1.f + ss));
}

// One fused pass per routing iteration:
//   a[c]   = dot_o(u_hat[b,c,s,:], v[b,c,:]) (+ b_old)   -> b_new (stored [b,s,c])
//   c_ij   = softmax_c(b_new);  s_partial += c_ij * u_hat
// Wave handles 4 s values for one b; lane = o. u_hat rows are RELOADED after the
// softmax (L1-hit) instead of kept live -> peak ~56 VGPRs, no spill.
// NO atomics: 4 waves LDS-reduce, wave 0 stores the per-(b,chunk) partial.
__global__ __launch_bounds__(256) void routing_pass(
    const float* __restrict__ u_hat, const float* __restrict__ v_in,
    float* __restrict__ b_io, float* __restrict__ parts, int read_b) {
    const int lane  = threadIdx.x & 63;
    const int wave  = threadIdx.x >> 6;
    const int b     = blockIdx.x >> 5;
    const int chunk = blockIdx.x & 31;

    float vl[C_];
#pragma unroll
    for (int c = 0; c < C_; ++c) vl[c] = v_in[((size_t)b * C_ + c) * DOUT_ + lane];

    float acc[C_];
#pragma unroll
    for (int c = 0; c < C_; ++c) acc[c] = 0.f;

#pragma unroll 1
    for (int i = 0; i < 4; ++i) {
        const int s = chunk * 16 + wave * 4 + i;
        const size_t ub = (((size_t)b * C_) * S_ + s) * DOUT_ + lane;  // + c*S_*DOUT_
        float a[C_];
#pragma unroll
        for (int c = 0; c < C_; ++c)
            a[c] = u_hat[ub + (size_t)c * S_ * DOUT_] * vl[c];
        // 16 independent wave reductions (butterfly -> every lane has full sum)
#pragma unroll
        for (int off = 32; off; off >>= 1) {
#pragma unroll
            for (int c = 0; c < C_; ++c) a[c] += __shfl_xor(a[c], off);
        }
        if (read_b) {
#pragma unroll
            for (int c = 0; c < C_; ++c)
                a[c] += b_io[((size_t)b * S_ + s) * C_ + c];
        }
        if (!read_b && lane == 0) {
            // b after this iter's update; only needed by the NEXT pass (skip on last).
#pragma unroll
            for (int c = 0; c < C_; ++c)
                b_io[((size_t)b * S_ + s) * C_ + c] = a[c];
        }
        // softmax over c
        float mx = a[0];
#pragma unroll
        for (int c = 1; c < C_; ++c) mx = fmaxf(mx, a[c]);
        float sum = 0.f;
#pragma unroll
        for (int c = 0; c < C_; ++c) { a[c] = __expf(a[c] - mx); sum += a[c]; }
        const float inv = 1.f / sum;
#pragma unroll
        for (int c = 0; c < C_; ++c)
            acc[c] += a[c] * inv * u_hat[ub + (size_t)c * S_ * DOUT_];
    }
    // cross-wave LDS reduce -> one non-atomic partial store per (b,chunk)
    __shared__ float red[4][C_][DOUT_];
#pragma unroll
    for (int c = 0; c < C_; ++c) red[wave][c][lane] = acc[c];
    __syncthreads();
    if (wave == 0) {
#pragma unroll
        for (int c = 0; c < C_; ++c) {
            const float t = red[0][c][lane] + red[1][c][lane]
                          + red[2][c][lane] + red[3][c][lane];
            parts[(((size_t)b * 32 + chunk) * C_ + c) * DOUT_ + lane] = t;
        }
    }
}

extern "C" void kernel_launch(void* const* d_in, const int* in_sizes, int n_in,
                              void* d_out, int out_size, void* d_ws, size_t ws_size,
                              hipStream_t stream) {
    const float* x = (const float*)d_in[0];
    const float* W = (const float*)d_in[1];

    float* u_hat = (float*)d_ws;                               // 16,777,216 f (64 MB)
    float* b_buf = u_hat + (size_t)B_ * C_ * S_ * DOUT_;       //    262,144 f (1 MB)  [b,s,c]
    float* parts = b_buf + (size_t)B_ * S_ * C_;               //  1,048,576 f (4 MB)  [b,32,c,o]
    float* v0    = parts + (size_t)B_ * 32 * C_ * DOUT_;       //     32,768 f
    float* v1    = v0 + (size_t)B_ * C_ * DOUT_;               //     32,768 f

    gemm_uhat<<<S_ * 4, 256, 0, stream>>>(x, W, u_hat);
    sum0_squash<<<B_ * C_, 1024, 0, stream>>>(u_hat, v0);
    routing_pass<<<B_ * 32, 256, 0, stream>>>(u_hat, v0, b_buf, parts, 0);
    part_squash<<<B_ * C_, 64, 0, stream>>>(parts, v1);
    routing_pass<<<B_ * 32, 256, 0, stream>>>(u_hat, v1, b_buf, parts, 1);
    part_squash<<<B_ * C_, 64, 0, stream>>>(parts, (float*)d_out);
}

// Round 2
// 744.491 us; speedup vs baseline: 1.0100x; 1.0100x over previous
//
#include <hip/hip_runtime.h>
#include <hip/hip_bf16.h>

#define B_    32
#define S_    512
#define C_    16
#define DIN_  256
#define DOUT_ 64

typedef __bf16 bf16x8 __attribute__((ext_vector_type(8)));
typedef float  f32x16 __attribute__((ext_vector_type(16)));

// Split fp32 -> bf16 hi + bf16 lo (lo = RNE(f - float(hi))); hi*hi + hi*lo + lo*hi
// reproduces the fp32 product to ~2^-17 relative.  (Numerics identical to the
// verified 752us kernel -- do not change, absmax budget is tight.)
__device__ inline void split2(float f, __bf16& hi, __bf16& lo) {
    hi = (__bf16)f;
    lo = (__bf16)(f - (float)hi);
}

// u_hat[b,c,s,o] = sum_i x[b,s,i] * W[c,s,i,o]  via MFMA 32x32x16 (split-bf16).
// R5 changes vs the 752us version:
//  - x[0:32,s,:] staged once per block into LDS (xs[32][260], float4-aligned pad):
//    kills the 32-scattered-line per-instruction x loads in the k-loop.
//  - W register double-buffer (wA/wB ping-pong): prefetch of k-block t+1 issues
//    BEFORE the convert+MFMA of k-block t -> HBM latency hides under compute.
//  - XCD-aware block remap: all 4 c-blocks of an s + 16 s's share an XCD (x L2 reuse).
// W streamed nontemporal (zero reuse; keep it out of L2/L3 so u_hat stays resident).
__global__ __launch_bounds__(256) void gemm_uhat(
    const float* __restrict__ x, const float* __restrict__ W,
    float* __restrict__ u_hat) {
    const int bid  = blockIdx.x;
    const int s    = (bid & 7) + ((bid >> 5) << 3);   // s_lo = xcd, s_hi = bid>>5
    const int cgrp = (bid >> 3) & 3;
    const int lane = threadIdx.x & 63;
    const int wid  = threadIdx.x >> 6;
    const int c    = (cgrp << 2) + wid;
    const int m    = lane & 31;                       // A row (b) / B col (o)
    const int kh   = lane >> 5;                       // k-half: k = kh*8 + j

    // ---- stage x tile (32 KB) : coalesced float4, 8 rows x 128B per instr ----
    __shared__ float xs[32][260];                     // +4 floats: 16B-aligned rows,
    {                                                 // bank rotation 4/row (b128 tiles)
        const int r  = threadIdx.x >> 3;              // 0..31
        const int c8 = threadIdx.x & 7;
        const float* xrow = x + ((size_t)r * S_ + s) * DIN_;
#pragma unroll
        for (int i = 0; i < 8; ++i) {
            const int c4 = c8 + 8 * i;                // 0..63 float4-columns
            *(float4*)&xs[r][c4 * 4] = *(const float4*)(xrow + c4 * 4);
        }
    }
    __syncthreads();

    const float* wp = W + (((size_t)c * S_ + s) * DIN_ + kh * 8) * DOUT_ + m;

    f32x16 acc0, acc1;
#pragma unroll
    for (int r = 0; r < 16; ++r) { acc0[r] = 0.f; acc1[r] = 0.f; }

    auto loadw = [&](float* d, const float* p) {
#pragma unroll
        for (int j = 0; j < 8; ++j) {
            d[j]     = __builtin_nontemporal_load(p + j * DOUT_);        // col m
            d[8 + j] = __builtin_nontemporal_load(p + j * DOUT_ + 32);   // col m+32
        }
    };

    auto compute = [&](int kb, const float* w) {
        const float* xr = &xs[m][kb * 16 + kh * 8];
        const float4 a0 = *(const float4*)(xr);       // ds_read_b128
        const float4 a1 = *(const float4*)(xr + 4);
        const float af[8] = {a0.x, a0.y, a0.z, a0.w, a1.x, a1.y, a1.z, a1.w};
        bf16x8 ahi, alo, b0hi, b0lo, b1hi, b1lo;
#pragma unroll
        for (int j = 0; j < 8; ++j) {
            __bf16 h, l;
            split2(af[j],   h, l); ahi[j] = h; alo[j] = l;
            split2(w[j],    h, l); b0hi[j] = h; b0lo[j] = l;
            split2(w[8+j],  h, l); b1hi[j] = h; b1lo[j] = l;
        }
        acc0 = __builtin_amdgcn_mfma_f32_32x32x16_bf16(ahi, b0hi, acc0, 0, 0, 0);
        acc0 = __builtin_amdgcn_mfma_f32_32x32x16_bf16(ahi, b0lo, acc0, 0, 0, 0);
        acc0 = __builtin_amdgcn_mfma_f32_32x32x16_bf16(alo, b0hi, acc0, 0, 0, 0);
        acc1 = __builtin_amdgcn_mfma_f32_32x32x16_bf16(ahi, b1hi, acc1, 0, 0, 0);
        acc1 = __builtin_amdgcn_mfma_f32_32x32x16_bf16(ahi, b1lo, acc1, 0, 0, 0);
        acc1 = __builtin_amdgcn_mfma_f32_32x32x16_bf16(alo, b1hi, acc1, 0, 0, 0);
    };

    float wA[16], wB[16];
    loadw(wA, wp);                                    // k-block 0
#pragma unroll 1
    for (int t = 0; t < 8; ++t) {
        loadw(wB, wp + 16 * DOUT_);                   // prefetch k-block 2t+1
        compute(2 * t, wA);
        const float* np = (t < 7) ? (wp + 32 * DOUT_) : wp;  // guard: no OOB on last
        loadw(wA, np);                                // prefetch k-block 2t+2
        compute(2 * t + 1, wB);
        wp += 32 * DOUT_;
    }

    // C/D layout (HW-verified m74/m101): col(o) = lane&31, row(b) = (r&3) + 8*(r>>2) + 4*kh
#pragma unroll
    for (int r = 0; r < 16; ++r) {
        const int b = (r & 3) + 8 * (r >> 2) + 4 * kh;
        const size_t base = (((size_t)b * C_ + c) * S_ + s) * DOUT_;
        u_hat[base + m]      = acc0[r];
        u_hat[base + m + 32] = acc1[r];
    }
}

// v0 = squash((1/16) * sum_s u_hat[b,c,s,:])  -- softmax of zero logits is uniform 1/C.
__global__ __launch_bounds__(1024) void sum0_squash(
    const float* __restrict__ u_hat, float* __restrict__ v_out) {
    const int lane = threadIdx.x & 63;
    const int w    = threadIdx.x >> 6;       // 0..15
    const int idx  = blockIdx.x;             // b*C + c
    const float* up = u_hat + (size_t)idx * S_ * DOUT_ + lane;
    float acc = 0.f;
#pragma unroll 4
    for (int s = w; s < S_; s += 16)
        acc += up[(size_t)s * DOUT_];
    __shared__ float red[16][DOUT_];
    red[w][lane] = acc;
    __syncthreads();
    if (w == 0) {
        float t = 0.f;
#pragma unroll
        for (int g = 0; g < 16; ++g) t += red[g][lane];
        t *= 0.0625f;
        float ss = t * t;
#pragma unroll
        for (int off = 32; off; off >>= 1) ss += __shfl_xor(ss, off);
        const float n = sqrtf(ss);
        v_out[(size_t)idx * DOUT_ + lane] = t * (n / (1.f + ss));
    }
}

// v = squash(sum_p parts[b,p,c,:]) -- final reduce of the 32 per-chunk partials + squash.
__global__ __launch_bounds__(64) void part_squash(
    const float* __restrict__ parts, float* __restrict__ dst) {
    const int lane = threadIdx.x;
    const int b = blockIdx.x >> 4;           // blockIdx = b*C + c
    const int c = blockIdx.x & 15;
    float t = 0.f;
#pragma unroll
    for (int p = 0; p < 32; ++p)
        t += parts[(((size_t)b * 32 + p) * C_ + c) * DOUT_ + lane];
    float ss = t * t;
#pragma unroll
    for (int off = 32; off; off >>= 1) ss += __shfl_xor(ss, off);
    const float n = sqrtf(ss);
    dst[(size_t)blockIdx.x * DOUT_ + lane] = t * (n / (1.f + ss));
}

// One fused pass per routing iteration.  R5: u_hat rows kept in registers (u0[16])
// across the softmax instead of re-loaded -> saves 64 MB of L2 reads per pass.
__global__ __launch_bounds__(256) void routing_pass(
    const float* __restrict__ u_hat, const float* __restrict__ v_in,
    float* __restrict__ b_io, float* __restrict__ parts, int read_b) {
    const int lane  = threadIdx.x & 63;
    const int wave  = threadIdx.x >> 6;
    const int b     = blockIdx.x >> 5;
    const int chunk = blockIdx.x & 31;

    float vl[C_];
#pragma unroll
    for (int c = 0; c < C_; ++c) vl[c] = v_in[((size_t)b * C_ + c) * DOUT_ + lane];

    float acc[C_];
#pragma unroll
    for (int c = 0; c < C_; ++c) acc[c] = 0.f;

#pragma unroll 1
    for (int i = 0; i < 4; ++i) {
        const int s = chunk * 16 + wave * 4 + i;
        const size_t ub = (((size_t)b * C_) * S_ + s) * DOUT_ + lane;  // + c*S_*DOUT_
        float u0[C_], a[C_];
#pragma unroll
        for (int c = 0; c < C_; ++c) {
            u0[c] = u_hat[ub + (size_t)c * S_ * DOUT_];
            a[c]  = u0[c] * vl[c];
        }
        // 16 independent wave reductions (butterfly -> every lane has full sum)
#pragma unroll
        for (int off = 32; off; off >>= 1) {
#pragma unroll
            for (int c = 0; c < C_; ++c) a[c] += __shfl_xor(a[c], off);
        }
        if (read_b) {
#pragma unroll
            for (int c = 0; c < C_; ++c)
                a[c] += b_io[((size_t)b * S_ + s) * C_ + c];
        }
        if (!read_b && lane == 0) {
            // b after this iter's update; only needed by the NEXT pass (skip on last).
#pragma unroll
            for (int c = 0; c < C_; ++c)
                b_io[((size_t)b * S_ + s) * C_ + c] = a[c];
        }
        // softmax over c
        float mx = a[0];
#pragma unroll
        for (int c = 1; c < C_; ++c) mx = fmaxf(mx, a[c]);
        float sum = 0.f;
#pragma unroll
        for (int c = 0; c < C_; ++c) { a[c] = __expf(a[c] - mx); sum += a[c]; }
        const float inv = 1.f / sum;
#pragma unroll
        for (int c = 0; c < C_; ++c)
            acc[c] += a[c] * inv * u0[c];
    }
    // cross-wave LDS reduce -> one non-atomic partial store per (b,chunk)
    __shared__ float red[4][C_][DOUT_];
#pragma unroll
    for (int c = 0; c < C_; ++c) red[wave][c][lane] = acc[c];
    __syncthreads();
    if (wave == 0) {
#pragma unroll
        for (int c = 0; c < C_; ++c) {
            const float t = red[0][c][lane] + red[1][c][lane]
                          + red[2][c][lane] + red[3][c][lane];
            parts[(((size_t)b * 32 + chunk) * C_ + c) * DOUT_ + lane] = t;
        }
    }
}

extern "C" void kernel_launch(void* const* d_in, const int* in_sizes, int n_in,
                              void* d_out, int out_size, void* d_ws, size_t ws_size,
                              hipStream_t stream) {
    const float* x = (const float*)d_in[0];
    const float* W = (const float*)d_in[1];

    float* u_hat = (float*)d_ws;                               // 16,777,216 f (64 MB)
    float* b_buf = u_hat + (size_t)B_ * C_ * S_ * DOUT_;       //    262,144 f (1 MB)  [b,s,c]
    float* parts = b_buf + (size_t)B_ * S_ * C_;               //  1,048,576 f (4 MB)  [b,32,c,o]
    float* v0    = parts + (size_t)B_ * 32 * C_ * DOUT_;       //     32,768 f
    float* v1    = v0 + (size_t)B_ * C_ * DOUT_;               //     32,768 f

    gemm_uhat<<<S_ * 4, 256, 0, stream>>>(x, W, u_hat);
    sum0_squash<<<B_ * C_, 1024, 0, stream>>>(u_hat, v0);
    routing_pass<<<B_ * 32, 256, 0, stream>>>(u_hat, v0, b_buf, parts, 0);
    part_squash<<<B_ * C_, 64, 0, stream>>>(parts, v1);
    routing_pass<<<B_ * 32, 256, 0, stream>>>(u_hat, v1, b_buf, parts, 1);
    part_squash<<<B_ * C_, 64, 0, stream>>>(parts, (float*)d_out);
}